// Round 2
// baseline (486.524 us; speedup 1.0000x reference)
//
#include <hip/hip_runtime.h>
#include <stdint.h>

typedef int v4i __attribute__((ext_vector_type(4)));

#define BM 128
#define BN 128
#define BK 64

// ---------------- workspace layout ----------------
// [0,64):          x absmax as uint bits (atomicMax target, memset to 0)
// [64, 64+16K):    w_scale[4096] fp32
// [32768, +M*K):   x_q int8  (33,554,432 B)
// [32768+M*K, +N*K): w_q int8 (16,777,216 B)
#define WS_WSCALE_OFF 64
#define WS_XQ_OFF 32768

__device__ __forceinline__ float fmax4abs(float4 v) {
  return fmaxf(fmaxf(fabsf(v.x), fabsf(v.y)), fmaxf(fabsf(v.z), fabsf(v.w)));
}

// ---------------- kernel 1: global absmax of x ----------------
__global__ __launch_bounds__(256) void absmax_kernel(const float4* __restrict__ x4,
                                                     unsigned* __restrict__ out, int n4) {
  float m = 0.f;
  for (int i = blockIdx.x * blockDim.x + threadIdx.x; i < n4; i += gridDim.x * blockDim.x) {
    m = fmaxf(m, fmax4abs(x4[i]));
  }
  #pragma unroll
  for (int off = 32; off > 0; off >>= 1) m = fmaxf(m, __shfl_down(m, off));
  __shared__ float sm[4];
  if ((threadIdx.x & 63) == 0) sm[threadIdx.x >> 6] = m;
  __syncthreads();
  if (threadIdx.x == 0) {
    m = fmaxf(fmaxf(sm[0], sm[1]), fmaxf(sm[2], sm[3]));
    atomicMax(out, __float_as_uint(m));  // bits-compare valid for non-negative floats
  }
}

// ---------------- kernel 2: per-row weight quantize ----------------
__global__ __launch_bounds__(256) void wquant_kernel(const float* __restrict__ w,
                                                     char* __restrict__ wq,
                                                     float* __restrict__ wscale, int K) {
  const int n = blockIdx.x;
  const float4* row = (const float4*)(w + (size_t)n * K);
  const int K4 = K >> 2;
  float m = 0.f;
  for (int i = threadIdx.x; i < K4; i += blockDim.x) m = fmaxf(m, fmax4abs(row[i]));
  #pragma unroll
  for (int off = 32; off > 0; off >>= 1) m = fmaxf(m, __shfl_xor(m, off));
  __shared__ float sm[4];
  if ((threadIdx.x & 63) == 0) sm[threadIdx.x >> 6] = m;
  __syncthreads();
  m = fmaxf(fmaxf(sm[0], sm[1]), fmaxf(sm[2], sm[3]));
  const float scale = fmaxf(m / 127.f, 1e-5f);
  if (threadIdx.x == 0) wscale[n] = scale;
  const float inv = 1.f / scale;
  char4* qrow = (char4*)(wq + (size_t)n * K);
  for (int i = threadIdx.x; i < K4; i += blockDim.x) {
    float4 v = row[i];
    char4 q;
    q.x = (char)(int)fminf(fmaxf(rintf(v.x * inv), -128.f), 127.f);
    q.y = (char)(int)fminf(fmaxf(rintf(v.y * inv), -128.f), 127.f);
    q.z = (char)(int)fminf(fmaxf(rintf(v.z * inv), -128.f), 127.f);
    q.w = (char)(int)fminf(fmaxf(rintf(v.w * inv), -128.f), 127.f);
    qrow[i] = q;
  }
}

// ---------------- kernel 3: per-tensor x quantize ----------------
__global__ __launch_bounds__(256) void xquant_kernel(const float4* __restrict__ x4,
                                                     char4* __restrict__ xq,
                                                     const unsigned* __restrict__ am, int n4) {
  const float scale = __uint_as_float(*am) / 127.f;  // no clamp in per-tensor branch
  const float inv = 1.f / scale;
  for (int i = blockIdx.x * blockDim.x + threadIdx.x; i < n4; i += gridDim.x * blockDim.x) {
    float4 v = x4[i];
    char4 q;
    q.x = (char)(int)fminf(fmaxf(rintf(v.x * inv), -128.f), 127.f);
    q.y = (char)(int)fminf(fmaxf(rintf(v.y * inv), -128.f), 127.f);
    q.z = (char)(int)fminf(fmaxf(rintf(v.z * inv), -128.f), 127.f);
    q.w = (char)(int)fminf(fmaxf(rintf(v.w * inv), -128.f), 127.f);
    xq[i] = q;
  }
}

// ---------------- kernel 4: int8 GEMM (m97 structure) ----------------
// A = x_q [M,K] row-major int8, B = w_q [N,K] row-major int8 (i.e. B^T layout)
// C[m,n] = (Σ_k A[m,k]*B[n,k]) * (x_scale*w_scale[n]) + bias[n]
__device__ __forceinline__ void gload16(const void* g, void* l) {
  __builtin_amdgcn_global_load_lds((const __attribute__((address_space(1))) void*)g,
                                   (__attribute__((address_space(3))) void*)l, 16, 0, 0);
}

__global__ __launch_bounds__(256) void gemm_i8_kernel(
    const char* __restrict__ Aq, const char* __restrict__ Bq,
    const float* __restrict__ wscale, const float* __restrict__ bias,
    const unsigned* __restrict__ am, float* __restrict__ out,
    int M, int N, int K) {
  __shared__ char As[BM * BK];
  __shared__ char Bs[BN * BK];
  const int tid = threadIdx.x;
  const int lane = tid & 63;
  const int wave = tid >> 6;
  const int wm = wave >> 1, wn = wave & 1;  // 2x2 waves, 64x64 output each
  const int brow = blockIdx.y * BM;
  const int bcol = blockIdx.x * BN;

  // staging: each thread loads 2x16B for A and 2x16B for B per K-step
  const char* aSrc0 = Aq + (size_t)(brow + (tid >> 2)) * K + (tid & 3) * 16;
  const char* aSrc1 = aSrc0 + (size_t)64 * K;
  const char* bSrc0 = Bq + (size_t)(bcol + (tid >> 2)) * K + (tid & 3) * 16;
  const char* bSrc1 = bSrc0 + (size_t)64 * K;
  char* aDst0 = &As[tid * 16];
  char* aDst1 = &As[4096 + tid * 16];
  char* bDst0 = &Bs[tid * 16];
  char* bDst1 = &Bs[4096 + tid * 16];

  v4i acc[4][4];
  #pragma unroll
  for (int i = 0; i < 4; ++i)
    #pragma unroll
    for (int j = 0; j < 4; ++j) acc[i][j] = (v4i)0;

  const int arow = wm * 64 + (lane & 15);   // fragment row within A tile
  const int brow_f = wn * 64 + (lane & 15); // fragment row within B tile
  const int koff = (lane >> 4) * 16;        // 16 consecutive K-bytes per lane

  for (int k0 = 0; k0 < K; k0 += BK) {
    gload16(aSrc0 + k0, aDst0);
    gload16(aSrc1 + k0, aDst1);
    gload16(bSrc0 + k0, bDst0);
    gload16(bSrc1 + k0, bDst1);
    __syncthreads();  // compiler emits vmcnt(0) drain before barrier

    v4i a[4], b[4];
    #pragma unroll
    for (int mi = 0; mi < 4; ++mi)
      a[mi] = *(const v4i*)&As[(arow + mi * 16) * BK + koff];
    #pragma unroll
    for (int ni = 0; ni < 4; ++ni)
      b[ni] = *(const v4i*)&Bs[(brow_f + ni * 16) * BK + koff];

    #pragma unroll
    for (int mi = 0; mi < 4; ++mi)
      #pragma unroll
      for (int ni = 0; ni < 4; ++ni)
        acc[mi][ni] = __builtin_amdgcn_mfma_i32_16x16x64_i8(a[mi], b[ni], acc[mi][ni], 0, 0, 0);
    __syncthreads();
  }

  // epilogue: C/D layout col=lane&15, row=(lane>>4)*4+reg (shape-determined)
  const float xscale = __uint_as_float(*am) / 127.f;
  #pragma unroll
  for (int ni = 0; ni < 4; ++ni) {
    const int n = bcol + wn * 64 + ni * 16 + (lane & 15);
    const float sc = xscale * wscale[n];
    const float bs = bias[n];
    #pragma unroll
    for (int mi = 0; mi < 4; ++mi) {
      const int mbase = brow + wm * 64 + mi * 16 + (lane >> 4) * 4;
      #pragma unroll
      for (int r = 0; r < 4; ++r)
        out[(size_t)(mbase + r) * N + n] = (float)acc[mi][ni][r] * sc + bs;
    }
  }
}

extern "C" void kernel_launch(void* const* d_in, const int* in_sizes, int n_in,
                              void* d_out, int out_size, void* d_ws, size_t ws_size,
                              hipStream_t stream) {
  const float* x = (const float*)d_in[0];       // [4,2048,4096] fp32
  const float* weight = (const float*)d_in[1];  // [4096,4096] fp32
  const float* bias = (const float*)d_in[2];    // [4096] fp32
  float* out = (float*)d_out;                   // [4,2048,4096] fp32

  const int M = 8192, N = 4096, K = 4096;

  char* ws = (char*)d_ws;
  unsigned* am = (unsigned*)ws;
  float* wscale = (float*)(ws + WS_WSCALE_OFF);
  char* xq = ws + WS_XQ_OFF;
  char* wq = ws + WS_XQ_OFF + (size_t)M * K;

  hipMemsetAsync(am, 0, 64, stream);

  const int n4 = (M * K) >> 2;  // 8,388,608 float4s
  absmax_kernel<<<2048, 256, 0, stream>>>((const float4*)x, am, n4);
  wquant_kernel<<<N, 256, 0, stream>>>(weight, wq, wscale, K);
  xquant_kernel<<<2048, 256, 0, stream>>>((const float4*)x, (char4*)xq, am, n4);

  dim3 grid(N / BN, M / BM);
  gemm_i8_kernel<<<grid, 256, 0, stream>>>(xq, wq, wscale, bias, am, out, M, N, K);
}

// Round 3
// 442.604 us; speedup vs baseline: 1.0992x; 1.0992x over previous
//
#include <hip/hip_runtime.h>
#include <stdint.h>

typedef int v4i __attribute__((ext_vector_type(4)));

// ---------------- workspace layout ----------------
// [0,64):            x absmax as uint bits (atomicMax target, memset to 0)
// [64, 64+16K):      w_scale[4096] fp32
// [32768, +M*K):     x_q int8  (33,554,432 B)
// [32768+M*K, +N*K): w_q int8 (16,777,216 B)
#define WS_WSCALE_OFF 64
#define WS_XQ_OFF 32768

__device__ __forceinline__ float fmax4abs(float4 v) {
  return fmaxf(fmaxf(fabsf(v.x), fabsf(v.y)), fmaxf(fabsf(v.z), fabsf(v.w)));
}

// ---------------- kernel 1: fused x-absmax + per-row weight quantize ----------------
// blocks [0,2048): grid-stride absmax over x;  blocks [2048,6144): wquant row n = bid-2048
__global__ __launch_bounds__(256) void prep_kernel(const float4* __restrict__ x4, int n4,
                                                   unsigned* __restrict__ am,
                                                   const float* __restrict__ w,
                                                   char* __restrict__ wq,
                                                   float* __restrict__ wscale, int K) {
  __shared__ float sm[4];
  if (blockIdx.x < 2048) {
    float m = 0.f;
    for (int i = blockIdx.x * blockDim.x + threadIdx.x; i < n4; i += 2048 * blockDim.x)
      m = fmaxf(m, fmax4abs(x4[i]));
    #pragma unroll
    for (int off = 32; off > 0; off >>= 1) m = fmaxf(m, __shfl_down(m, off));
    if ((threadIdx.x & 63) == 0) sm[threadIdx.x >> 6] = m;
    __syncthreads();
    if (threadIdx.x == 0) {
      m = fmaxf(fmaxf(sm[0], sm[1]), fmaxf(sm[2], sm[3]));
      atomicMax(am, __float_as_uint(m));  // bits-compare valid for non-negative floats
    }
  } else {
    const int n = blockIdx.x - 2048;
    const float4* row = (const float4*)(w + (size_t)n * K);
    const int K4 = K >> 2;
    float m = 0.f;
    for (int i = threadIdx.x; i < K4; i += blockDim.x) m = fmaxf(m, fmax4abs(row[i]));
    #pragma unroll
    for (int off = 32; off > 0; off >>= 1) m = fmaxf(m, __shfl_xor(m, off));
    if ((threadIdx.x & 63) == 0) sm[threadIdx.x >> 6] = m;
    __syncthreads();
    m = fmaxf(fmaxf(sm[0], sm[1]), fmaxf(sm[2], sm[3]));
    const float scale = fmaxf(m / 127.f, 1e-5f);
    if (threadIdx.x == 0) wscale[n] = scale;
    const float inv = 1.f / scale;
    char4* qrow = (char4*)(wq + (size_t)n * K);
    for (int i = threadIdx.x; i < K4; i += blockDim.x) {
      float4 v = row[i];
      char4 q;
      q.x = (char)(int)fminf(fmaxf(rintf(v.x * inv), -128.f), 127.f);
      q.y = (char)(int)fminf(fmaxf(rintf(v.y * inv), -128.f), 127.f);
      q.z = (char)(int)fminf(fmaxf(rintf(v.z * inv), -128.f), 127.f);
      q.w = (char)(int)fminf(fmaxf(rintf(v.w * inv), -128.f), 127.f);
      qrow[i] = q;
    }
  }
}

// ---------------- kernel 2: per-tensor x quantize ----------------
__global__ __launch_bounds__(256) void xquant_kernel(const float4* __restrict__ x4,
                                                     char4* __restrict__ xq,
                                                     const unsigned* __restrict__ am, int n4) {
  const float scale = __uint_as_float(*am) / 127.f;  // no clamp in per-tensor branch
  const float inv = 1.f / scale;
  for (int i = blockIdx.x * blockDim.x + threadIdx.x; i < n4; i += gridDim.x * blockDim.x) {
    float4 v = x4[i];
    char4 q;
    q.x = (char)(int)fminf(fmaxf(rintf(v.x * inv), -128.f), 127.f);
    q.y = (char)(int)fminf(fmaxf(rintf(v.y * inv), -128.f), 127.f);
    q.z = (char)(int)fminf(fmaxf(rintf(v.z * inv), -128.f), 127.f);
    q.w = (char)(int)fminf(fmaxf(rintf(v.w * inv), -128.f), 127.f);
    xq[i] = q;
  }
}

// ---------------- kernel 3: int8 GEMM, 256^2 tile, ring-4 pipelined ----------------
// A = x_q [M,K] int8 row-major, B = w_q [N,K] int8 row-major.
// C[m,n] = (sum_k A[m,k]B[n,k]) * xscale*wscale[n] + bias[n]
//
// Geometry: BM=BN=256, BK=64 bytes; 512 thr = 8 waves (2M x 4N); per-wave out 128x64.
// LDS: 4 ring buffers x (A 16KB + B 16KB) = 128 KiB dynamic.
// Per K-tile: 2 phases x {stage 2 gload_lds (tile t+3) | ds_read 8/4 b128 | bar |
//   prio1 | 16 x mfma_i32_16x16x64_i8 | prio0 | bar}; s_waitcnt vmcnt(8) once per tile.
// T2 swizzle: slot ^= row&3 (involution) on both pre-swizzled global src and ds_read addr.
__device__ __forceinline__ void gload16(const void* g, void* l) {
  __builtin_amdgcn_global_load_lds((const __attribute__((address_space(1))) void*)g,
                                   (__attribute__((address_space(3))) void*)l, 16, 0, 0);
}

#define NT 64  // K / 64

__global__ __launch_bounds__(512, 1) void gemm_i8_8p(
    const char* __restrict__ Aq, const char* __restrict__ Bq,
    const float* __restrict__ wscale, const float* __restrict__ bias,
    const unsigned* __restrict__ am, float* __restrict__ out,
    int M, int N, int K) {
  extern __shared__ char smem[];  // 131072 B
  const int tid = threadIdx.x;
  const int lane = tid & 63;
  const int wave = tid >> 6;
  const int wm = wave >> 2;  // 0..1  -> rows wm*128..+127
  const int wn = wave & 3;   // 0..3  -> cols wn*64..+63

  // T1: XCD-aware block swizzle (512 blocks, 8 XCDs -> 64 contiguous per XCD)
  const int bid = blockIdx.x;
  const int swz = (bid & 7) * 64 + (bid >> 3);
  const int brow = (swz >> 4) * 256;   // 32 tiles in M
  const int bcol = (swz & 15) * 256;   // 16 tiles in N

  // staging source (pre-swizzled global address; LDS dest stays linear)
  const int srow = tid >> 2;                          // 0..127
  const int scol = ((tid & 3) ^ (srow & 3)) * 16;     // swizzled 16B slot
  const char* aS0 = Aq + (size_t)(brow + srow) * K + scol;
  const char* aS1 = aS0 + (size_t)128 * K;
  const char* bS0 = Bq + (size_t)(bcol + srow) * K + scol;
  const char* bS1 = bS0 + (size_t)128 * K;

  // ds_read bases (swizzled): row&3 == lane&3 for all fragments
  const int rswz = ((lane >> 4) ^ (lane & 3)) * 16;
  const int aRd = (wm * 128 + (lane & 15)) * 64 + rswz;  // + mf*1024
  const int bRd = (wn * 64 + (lane & 15)) * 64 + rswz;   // + nf*1024

  v4i acc[8][4];
  #pragma unroll
  for (int i = 0; i < 8; ++i)
    #pragma unroll
    for (int j = 0; j < 4; ++j) acc[i][j] = (v4i)0;

  // prologue: stage tiles 0,1,2 (4 gload_lds each per thread)
  #pragma unroll
  for (int pt = 0; pt < 3; ++pt) {
    char* bufN = smem + pt * 32768;
    gload16(aS0 + pt * 64, bufN + tid * 16);
    gload16(aS1 + pt * 64, bufN + 8192 + tid * 16);
    gload16(bS0 + pt * 64, bufN + 16384 + tid * 16);
    gload16(bS1 + pt * 64, bufN + 16384 + 8192 + tid * 16);
  }

  for (int t = 0; t < NT; ++t) {
    // tile-top fence: tile t resident; tiles t+1,t+2 (8 loads) stay in flight
    if (t < NT - 2)      asm volatile("s_waitcnt vmcnt(8)" ::: "memory");
    else if (t == NT - 2) asm volatile("s_waitcnt vmcnt(4)" ::: "memory");
    else                 asm volatile("s_waitcnt vmcnt(0)" ::: "memory");
    __builtin_amdgcn_s_barrier();

    const char* bufA = smem + (t & 3) * 32768;
    char* bufN = smem + ((t + 3) & 3) * 32768;

    // ---- phase 0: stage A of tile t+3; read A(mf0-3)+B(nf0-3); 16 MFMA ----
    if (t + 3 < NT) {
      gload16(aS0 + (t + 3) * 64, bufN + tid * 16);
      gload16(aS1 + (t + 3) * 64, bufN + 8192 + tid * 16);
    }
    v4i a[4], b[4];
    #pragma unroll
    for (int nf = 0; nf < 4; ++nf)
      b[nf] = *(const v4i*)(bufA + 16384 + bRd + nf * 1024);
    #pragma unroll
    for (int mf = 0; mf < 4; ++mf)
      a[mf] = *(const v4i*)(bufA + aRd + mf * 1024);
    __builtin_amdgcn_s_barrier();
    __builtin_amdgcn_s_setprio(1);
    #pragma unroll
    for (int mf = 0; mf < 4; ++mf)
      #pragma unroll
      for (int nf = 0; nf < 4; ++nf)
        acc[mf][nf] = __builtin_amdgcn_mfma_i32_16x16x64_i8(a[mf], b[nf], acc[mf][nf], 0, 0, 0);
    __builtin_amdgcn_s_setprio(0);
    __builtin_amdgcn_s_barrier();

    // ---- phase 1: stage B of tile t+3; read A(mf4-7); 16 MFMA ----
    if (t + 3 < NT) {
      gload16(bS0 + (t + 3) * 64, bufN + 16384 + tid * 16);
      gload16(bS1 + (t + 3) * 64, bufN + 16384 + 8192 + tid * 16);
    }
    #pragma unroll
    for (int mf = 0; mf < 4; ++mf)
      a[mf] = *(const v4i*)(bufA + aRd + (mf + 4) * 1024);
    __builtin_amdgcn_s_barrier();
    __builtin_amdgcn_s_setprio(1);
    #pragma unroll
    for (int mf = 0; mf < 4; ++mf)
      #pragma unroll
      for (int nf = 0; nf < 4; ++nf)
        acc[mf + 4][nf] = __builtin_amdgcn_mfma_i32_16x16x64_i8(a[mf], b[nf], acc[mf + 4][nf], 0, 0, 0);
    __builtin_amdgcn_s_setprio(0);
    // no trailing barrier: next tile-top [vmcnt; s_barrier] provides it
  }

  // epilogue: C/D layout col=lane&15 (=n), row=(lane>>4)*4+r (=m) — verified round 2
  const float xscale = __uint_as_float(*am) / 127.f;
  #pragma unroll
  for (int nf = 0; nf < 4; ++nf) {
    const int n = bcol + wn * 64 + nf * 16 + (lane & 15);
    const float sc = xscale * wscale[n];
    const float bs = bias[n];
    #pragma unroll
    for (int mf = 0; mf < 8; ++mf) {
      const int mbase = brow + wm * 128 + mf * 16 + (lane >> 4) * 4;
      #pragma unroll
      for (int r = 0; r < 4; ++r)
        out[(size_t)(mbase + r) * N + n] = (float)acc[mf][nf][r] * sc + bs;
    }
  }
}

extern "C" void kernel_launch(void* const* d_in, const int* in_sizes, int n_in,
                              void* d_out, int out_size, void* d_ws, size_t ws_size,
                              hipStream_t stream) {
  const float* x = (const float*)d_in[0];       // [4,2048,4096] fp32
  const float* weight = (const float*)d_in[1];  // [4096,4096] fp32
  const float* bias = (const float*)d_in[2];    // [4096] fp32
  float* out = (float*)d_out;                   // [4,2048,4096] fp32

  const int M = 8192, N = 4096, K = 4096;

  char* ws = (char*)d_ws;
  unsigned* am = (unsigned*)ws;
  float* wscale = (float*)(ws + WS_WSCALE_OFF);
  char* xq = ws + WS_XQ_OFF;
  char* wq = ws + WS_XQ_OFF + (size_t)M * K;

  hipMemsetAsync(am, 0, 64, stream);

  const int n4 = (M * K) >> 2;
  prep_kernel<<<2048 + N, 256, 0, stream>>>((const float4*)x, n4, am, weight, wq, wscale, K);
  xquant_kernel<<<2048, 256, 0, stream>>>((const float4*)x, (char4*)xq, am, n4);

  (void)hipFuncSetAttribute(reinterpret_cast<const void*>(gemm_i8_8p),
                            hipFuncAttributeMaxDynamicSharedMemorySize, 131072);
  gemm_i8_8p<<<512, 512, 131072, stream>>>(xq, wq, wscale, bias, am, out, M, N, K);
}